// Round 15
// baseline (77.814 us; speedup 1.0000x reference)
//
#include <hip/hip_runtime.h>
#include <hip/hip_bf16.h>
#include <math.h>

#define NUM_EXPERTS 64
#define HIDDEN      4096
#define T_TOKENS    16384   // B*S

using short8 = __attribute__((ext_vector_type(8))) short;   // 8 bf16
using f32x4  = __attribute__((ext_vector_type(4))) float;

// (f0,f1) -> packed bf16 hi (f0 in low 16) + packed bf16 lo residuals.
__device__ __forceinline__ unsigned pack_pair(float f0, float f1, unsigned& lopk) {
    __hip_bfloat162 h2 = __float22bfloat162_rn(make_float2(f0, f1));
    unsigned hb; __builtin_memcpy(&hb, &h2, 4);
    float h0 = __builtin_bit_cast(float, hb << 16);
    float h1 = __builtin_bit_cast(float, hb & 0xffff0000u);
    __hip_bfloat162 l2 = __float22bfloat162_rn(make_float2(f0 - h0, f1 - h1));
    unsigned lb; __builtin_memcpy(&lb, &l2, 4);
    lopk = lb;
    return hb;
}
__device__ __forceinline__ void split8(const float4 a, const float4 b, uint4& hi, uint4& lo) {
    hi.x = pack_pair(a.x, a.y, lo.x);
    hi.y = pack_pair(a.z, a.w, lo.y);
    hi.z = pack_pair(b.x, b.y, lo.z);
    hi.w = pack_pair(b.z, b.w, lo.w);
}

#define MFMA(a, b, c) __builtin_amdgcn_mfma_f32_16x16x32_bf16((a), (b), (c), 0, 0, 0)

// async global->LDS, 16 B per lane (zero VGPR cost).
#define GLOAD16(g_, l_)                                                        \
    __builtin_amdgcn_global_load_lds(                                          \
        (__attribute__((address_space(1))) unsigned*)(void*)(g_),              \
        (__attribute__((address_space(3))) unsigned*)(void*)(l_), 16, 0, 0)

#define WAITVM(n_)  asm volatile("s_waitcnt vmcnt(" #n_ ")" ::: "memory")
#define WAITLG()    asm volatile("s_waitcnt lgkmcnt(0)" ::: "memory")
#define SB()        __builtin_amdgcn_sched_barrier(0)

// ---- pre-kernel: split W [64][4096] f32 into fragment-ordered bf16 hi/lo planes.
// Fragment j = ((t*4 + nt)*64 + lane), t = global K-chunk (k/32).
__global__ __launch_bounds__(256) void w_split_kernel(
    const float* __restrict__ W, unsigned char* __restrict__ ws)
{
    const int j  = blockIdx.x * 256 + threadIdx.x;   // 0..32767
    const int l  = j & 63;
    const int nt = (j >> 6) & 3;
    const int t  = j >> 8;
    const int e  = nt * 16 + (l & 15);
    const int k0 = t * 32 + ((l >> 4) & 3) * 8;
    const float* p = W + (size_t)e * HIDDEN + k0;
    float4 w0 = *reinterpret_cast<const float4*>(p);
    float4 w1 = *reinterpret_cast<const float4*>(p + 4);
    uint4 hi, lo;
    split8(w0, w1, hi, lo);
    *reinterpret_cast<uint4*>(ws + (size_t)j * 16)            = hi;
    *reinterpret_cast<uint4*>(ws + 524288 + (size_t)j * 16)   = lo;
}

// ---- main kernel: block = 128 tokens x K-half; 8 waves, each owning a
// K-sixteenth (256 k = 8 chunks) over 8 M-tiles. Sub-chunk (4 M-tile, 8 KB)
// staging keeps LDS at 16 KB/wave -> 8 waves/block -> 2 waves/SIMD, while
// BM=128 keeps W traffic at 128 MB. Counted vmcnt, zero mid-loop barriers.

#define LOAD_W(dst, t_) do {                                                   \
    const unsigned char* pW_ = wsHi + (size_t)(tBase + (t_)) * 4096 + laneOff; \
    _Pragma("unroll")                                                          \
    for (int nt_ = 0; nt_ < 4; ++nt_) {                                        \
        dst[nt_]     = *reinterpret_cast<const uint4*>(pW_ + nt_ * 1024);      \
        dst[nt_ + 4] = *reinterpret_cast<const uint4*>(pW_ + 524288 + nt_ * 1024); \
    } } while (0)

// Stage sub-chunk s_ (chunk t=s_/2, M-tiles (s_%2)*4..+3) into buf[s_%2].
#define STAGE_S(s_) do {                                                       \
    unsigned char* ld_ = smem + (size_t)w * 16384 + ((s_) & 1) * 8192;         \
    const float* g0_ = aBase + (size_t)((s_) >> 1) * 32                        \
                             + (size_t)(((s_) & 1) * 4) * 16 * HIDDEN;         \
    _Pragma("unroll")                                                          \
    for (int mt_ = 0; mt_ < 4; ++mt_) {                                        \
        const float* g_ = g0_ + (size_t)mt_ * 16 * HIDDEN;                     \
        GLOAD16(g_,     ld_ + mt_ * 2048);                                     \
        GLOAD16(g_ + 4, ld_ + mt_ * 2048 + 1024);                              \
    } } while (0)

// Body of sub-chunk s_: dsread buf -> lgkm -> [W(t+1) at even s_] ->
// stage(s_+2) -> split+MFMA into acc[(s_%2)*4 .. +3].
#define SUB_BODY(s_, wCur_, wNxt_) do {                                        \
    SB();                                                                      \
    const unsigned char* ls_ = smem + (size_t)w * 16384 + ((s_) & 1) * 8192 + laneOff; \
    float4 q_[4][2];                                                           \
    _Pragma("unroll")                                                          \
    for (int i_ = 0; i_ < 4; ++i_) {                                           \
        q_[i_][0] = *reinterpret_cast<const float4*>(ls_ + i_ * 2048);         \
        q_[i_][1] = *reinterpret_cast<const float4*>(ls_ + i_ * 2048 + 1024);  \
    }                                                                          \
    WAITLG(); SB();                                                            \
    if ((((s_) & 1) == 0) && ((s_) / 2 + 1 < 8)) LOAD_W(wNxt_, (s_) / 2 + 1);  \
    if ((s_) + 2 < 16) STAGE_S((s_) + 2);                                      \
    _Pragma("unroll")                                                          \
    for (int i_ = 0; i_ < 4; ++i_) {                                           \
        uint4 hi_, lo_;                                                        \
        split8(q_[i_][0], q_[i_][1], hi_, lo_);                                \
        short8 ah_ = __builtin_bit_cast(short8, hi_);                          \
        short8 al_ = __builtin_bit_cast(short8, lo_);                          \
        _Pragma("unroll")                                                      \
        for (int nt_ = 0; nt_ < 4; ++nt_) {                                    \
            short8 wh_ = __builtin_bit_cast(short8, wCur_[nt_]);               \
            short8 wl_ = __builtin_bit_cast(short8, wCur_[nt_ + 4]);           \
            acc[((s_) & 1) * 4 + i_][nt_] = MFMA(ah_, wh_, acc[((s_) & 1) * 4 + i_][nt_]); \
            acc[((s_) & 1) * 4 + i_][nt_] = MFMA(ah_, wl_, acc[((s_) & 1) * 4 + i_][nt_]); \
            acc[((s_) & 1) * 4 + i_][nt_] = MFMA(al_, wh_, acc[((s_) & 1) * 4 + i_][nt_]); \
        } }                                                                    \
} while (0)

// Steady state in-flight at entry: even s: {W(t),stage(s),stage(s+1)}=24 ->
// vmcnt(8); odd s: {stage(s),W(t+1),stage(s+1)}... = 24 -> vmcnt(16);
// s=15: {stage(15)}=8 -> vmcnt(0).
#define SUB_E(s_, wC_, wN_) do { WAITVM(8);  SUB_BODY(s_, wC_, wN_); } while (0)
#define SUB_O(s_, wC_, wN_) do { WAITVM(16); SUB_BODY(s_, wC_, wN_); } while (0)
#define SUB_Z(s_, wC_, wN_) do { WAITVM(0);  SUB_BODY(s_, wC_, wN_); } while (0)

__global__ __launch_bounds__(512, 2) void router_gemm_partial(
    const float* __restrict__ A,
    const unsigned char* __restrict__ wsHi,   // frag-ordered W hi; lo at +512KB
    float* __restrict__ partG)                // [2][T][64] f32
{
    // [0,128K): per-wave A staging (wave w: [w*16K, +16K), 2 x 8 KB buffers).
    // Reused as the 128 KB combine scratch part[4][8][4][64] afterwards.
    __shared__ unsigned char smem[131072];

    const int tid  = threadIdx.x;
    const int lane = tid & 63;
    const int w    = tid >> 6;                // wave id (0..7) = K-sixteenth
    const int ky   = blockIdx.y;              // K-half (0..1)
    const int tok0 = blockIdx.x * 128;
    const int tBase = ky * 64 + w * 8;        // global chunk base (chunks of 32k)

    const float* aBase = A + (size_t)(tok0 + (lane & 15)) * HIDDEN
                           + ky * 2048 + w * 256 + ((lane >> 4) & 3) * 8;
    const int laneOff = lane * 16;

    f32x4 acc[8][4];
#pragma unroll
    for (int mt = 0; mt < 8; ++mt)
#pragma unroll
        for (int nt = 0; nt < 4; ++nt) acc[mt][nt] = (f32x4){0.f, 0.f, 0.f, 0.f};

    uint4 wX[8], wY[8];          // W ping-pong (hi 0..3, lo 4..7)

    // Prologue: W(0) first (oldest), then sub 0, sub 1.
    LOAD_W(wX, 0);
    STAGE_S(0);
    STAGE_S(1);

    SUB_E( 0, wX, wY);  SUB_O( 1, wX, wY);    // chunk 0 (W = wX)
    SUB_E( 2, wY, wX);  SUB_O( 3, wY, wX);    // chunk 1
    SUB_E( 4, wX, wY);  SUB_O( 5, wX, wY);    // chunk 2
    SUB_E( 6, wY, wX);  SUB_O( 7, wY, wX);    // chunk 3
    SUB_E( 8, wX, wY);  SUB_O( 9, wX, wY);    // chunk 4
    SUB_E(10, wY, wX);  SUB_O(11, wY, wX);    // chunk 5
    SUB_E(12, wX, wY);  SUB_O(13, wX, wY);    // chunk 6
    SUB_E(14, wY, wX);  SUB_Z(15, wY, wX);    // chunk 7

    // ---- in-block combine over 8 waves: 0-3 write, 4-7 RMW-add, then
    // wave w<4 reduces q=0..3 for M-tiles 2w,2w+1, writes fp32 partials.
    f32x4 (*part)[8][4][64] = reinterpret_cast<f32x4 (*)[8][4][64]>(smem);

    __syncthreads();
    if (w < 4) {
#pragma unroll
        for (int mt = 0; mt < 8; ++mt)
#pragma unroll
            for (int nt = 0; nt < 4; ++nt) part[w][mt][nt][lane] = acc[mt][nt];
    }
    __syncthreads();
    if (w >= 4) {
#pragma unroll
        for (int mt = 0; mt < 8; ++mt)
#pragma unroll
            for (int nt = 0; nt < 4; ++nt)
                part[w - 4][mt][nt][lane] = part[w - 4][mt][nt][lane] + acc[mt][nt];
    }
    __syncthreads();

    if (w < 4) {
#pragma unroll
        for (int j = 0; j < 2; ++j) {
            const int mt = 2 * w + j;
#pragma unroll
            for (int nt = 0; nt < 4; ++nt) {
                f32x4 s = part[0][mt][nt][lane];
#pragma unroll
                for (int q = 1; q < 4; ++q) s = s + part[q][mt][nt][lane];
                const int e = nt * 16 + (lane & 15);
#pragma unroll
                for (int r = 0; r < 4; ++r) {
                    const int tok = tok0 + mt * 16 + (lane >> 4) * 4 + r;
                    partG[((size_t)ky * T_TOKENS + tok) * 64 + e] = s[r];
                }
            }
        }
    }
}

// ---- combine kernel: sum the 2 K-halves per token, top-2 ----
__global__ __launch_bounds__(64) void combine_topk(
    const float* __restrict__ partG,   // [2][T][64]
    float* __restrict__ out)
{
    const int tok = blockIdx.x * 64 + threadIdx.x;
    const float4* p0 = reinterpret_cast<const float4*>(partG + (size_t)tok * 64);
    const float4* p1 = reinterpret_cast<const float4*>(partG + ((size_t)T_TOKENS + tok) * 64);

    float s[64];
#pragma unroll
    for (int i = 0; i < 16; ++i) {
        float4 a = p0[i], b = p1[i];
        s[4*i+0] = a.x + b.x; s[4*i+1] = a.y + b.y;
        s[4*i+2] = a.z + b.z; s[4*i+3] = a.w + b.w;
    }

    float b1 = -INFINITY, b2 = -INFINITY;
    int i1 = 0, i2 = 0;
#pragma unroll
    for (int e = 0; e < NUM_EXPERTS; ++e) {
        float v = s[e];
        if (v > b1)      { b2 = b1; i2 = i1; b1 = v; i1 = e; }
        else if (v > b2) { b2 = v;  i2 = e; }
    }
    out[(size_t)tok * 2 + 0] = b1;
    out[(size_t)tok * 2 + 1] = b2;
    out[(size_t)2 * T_TOKENS + (size_t)tok * 2 + 0] = (float)i1;
    out[(size_t)2 * T_TOKENS + (size_t)tok * 2 + 1] = (float)i2;
}

extern "C" void kernel_launch(void* const* d_in, const int* in_sizes, int n_in,
                              void* d_out, int out_size, void* d_ws, size_t ws_size,
                              hipStream_t stream) {
    const float* A = (const float*)d_in[0];   // hidden_states fp32 [16384,4096]
    const float* W = (const float*)d_in[1];   // W fp32 [64,4096]
    float* out = (float*)d_out;
    unsigned char* ws = (unsigned char*)d_ws;
    // ws layout: [0,1MB) W hi/lo planes; [1MB, 1MB+8MB) fp32 partials [2][T][64]
    float* partG = reinterpret_cast<float*>(ws + (1 << 20));

    w_split_kernel<<<dim3(128), dim3(256), 0, stream>>>(W, ws);
    router_gemm_partial<<<dim3(T_TOKENS / 128, 2), dim3(512), 0, stream>>>(A, ws, partG);
    combine_topk<<<dim3(T_TOKENS / 64), dim3(64), 0, stream>>>(partG, out);
}

// Round 17
// 64.965 us; speedup vs baseline: 1.1978x; 1.1978x over previous
//
#include <hip/hip_runtime.h>
#include <hip/hip_bf16.h>
#include <math.h>

#define NUM_EXPERTS 64
#define HIDDEN      4096
#define T_TOKENS    16384   // B*S

using short8 = __attribute__((ext_vector_type(8))) short;   // 8 bf16
using f32x4  = __attribute__((ext_vector_type(4))) float;

// (f0,f1) -> packed bf16 hi (f0 in low 16) + packed bf16 lo residuals.
__device__ __forceinline__ unsigned pack_pair(float f0, float f1, unsigned& lopk) {
    __hip_bfloat162 h2 = __float22bfloat162_rn(make_float2(f0, f1));
    unsigned hb; __builtin_memcpy(&hb, &h2, 4);
    float h0 = __builtin_bit_cast(float, hb << 16);
    float h1 = __builtin_bit_cast(float, hb & 0xffff0000u);
    __hip_bfloat162 l2 = __float22bfloat162_rn(make_float2(f0 - h0, f1 - h1));
    unsigned lb; __builtin_memcpy(&lb, &l2, 4);
    lopk = lb;
    return hb;
}
__device__ __forceinline__ void split8(const float4 a, const float4 b, uint4& hi, uint4& lo) {
    hi.x = pack_pair(a.x, a.y, lo.x);
    hi.y = pack_pair(a.z, a.w, lo.y);
    hi.z = pack_pair(b.x, b.y, lo.z);
    hi.w = pack_pair(b.z, b.w, lo.w);
}

#define MFMA(a, b, c) __builtin_amdgcn_mfma_f32_16x16x32_bf16((a), (b), (c), 0, 0, 0)

// async global->LDS, 16 B per lane (zero VGPR cost).
#define GLOAD16(g_, l_)                                                        \
    __builtin_amdgcn_global_load_lds(                                          \
        (__attribute__((address_space(1))) unsigned*)(void*)(g_),              \
        (__attribute__((address_space(3))) unsigned*)(void*)(l_), 16, 0, 0)

#define WAITVM(n_)  asm volatile("s_waitcnt vmcnt(" #n_ ")" ::: "memory")
#define WAITLG()    asm volatile("s_waitcnt lgkmcnt(0)" ::: "memory")
#define SB()        __builtin_amdgcn_sched_barrier(0)

// ---- pre-kernel: split W [64][4096] f32 into fragment-ordered bf16 hi/lo planes.
// Fragment j = ((t*4 + nt)*64 + lane), t = global K-chunk (k/32).
__global__ __launch_bounds__(256) void w_split_kernel(
    const float* __restrict__ W, unsigned char* __restrict__ ws)
{
    const int j  = blockIdx.x * 256 + threadIdx.x;   // 0..32767
    const int l  = j & 63;
    const int nt = (j >> 6) & 3;
    const int t  = j >> 8;
    const int e  = nt * 16 + (l & 15);
    const int k0 = t * 32 + ((l >> 4) & 3) * 8;
    const float* p = W + (size_t)e * HIDDEN + k0;
    float4 w0 = *reinterpret_cast<const float4*>(p);
    float4 w1 = *reinterpret_cast<const float4*>(p + 4);
    uint4 hi, lo;
    split8(w0, w1, hi, lo);
    *reinterpret_cast<uint4*>(ws + (size_t)j * 16)            = hi;
    *reinterpret_cast<uint4*>(ws + 524288 + (size_t)j * 16)   = lo;
}

// ---- main kernel: block = 128 tokens x K-half; 8 waves, each owning a
// K-sixteenth (256 k = 8 chunks) over 8 M-tiles. Sub-chunk (4 M-tile, 8 KB)
// staging -> 16 KB/wave LDS -> 8 waves/block -> 2 waves/SIMD; BM=128 keeps
// W traffic at 128 MB. Counted vmcnt, zero mid-loop barriers.
// R17 = R16's low-register grouping with the RAW hazard fixed: STAGE_S(s+2)
// (which overwrites the buffer being consumed) is issued only AFTER the
// second group's ds_reads have completed (lgkmcnt(0)).

#define LOAD_W(dst, t_) do {                                                   \
    const unsigned char* pW_ = wsHi + (size_t)(tBase + (t_)) * 4096 + laneOff; \
    _Pragma("unroll")                                                          \
    for (int nt_ = 0; nt_ < 4; ++nt_) {                                        \
        dst[nt_]     = *reinterpret_cast<const uint4*>(pW_ + nt_ * 1024);      \
        dst[nt_ + 4] = *reinterpret_cast<const uint4*>(pW_ + 524288 + nt_ * 1024); \
    } } while (0)

// Stage sub-chunk s_ (chunk t=s_/2, M-tiles (s_%2)*4..+3) into buf[s_%2].
#define STAGE_S(s_) do {                                                       \
    unsigned char* ld_ = smem + (size_t)w * 16384 + ((s_) & 1) * 8192;         \
    const float* g0_ = aBase + (size_t)((s_) >> 1) * 32                        \
                             + (size_t)(((s_) & 1) * 4) * 16 * HIDDEN;         \
    _Pragma("unroll")                                                          \
    for (int mt_ = 0; mt_ < 4; ++mt_) {                                        \
        const float* g_ = g0_ + (size_t)mt_ * 16 * HIDDEN;                     \
        GLOAD16(g_,     ld_ + mt_ * 2048);                                     \
        GLOAD16(g_ + 4, ld_ + mt_ * 2048 + 1024);                              \
    } } while (0)

// split + 6 MFMA for one M-tile from a 2-float4 pair.
#define TILE_MFMA(q0_, q1_, mt_, wb_) do {                                     \
    uint4 hi_, lo_;                                                            \
    split8(q0_, q1_, hi_, lo_);                                                \
    short8 ah_ = __builtin_bit_cast(short8, hi_);                              \
    short8 al_ = __builtin_bit_cast(short8, lo_);                              \
    _Pragma("unroll")                                                          \
    for (int nt_ = 0; nt_ < 4; ++nt_) {                                        \
        short8 wh_ = __builtin_bit_cast(short8, wb_[nt_]);                     \
        short8 wl_ = __builtin_bit_cast(short8, wb_[nt_ + 4]);                 \
        acc[mt_][nt_] = MFMA(ah_, wh_, acc[mt_][nt_]);                         \
        acc[mt_][nt_] = MFMA(ah_, wl_, acc[mt_][nt_]);                         \
        acc[mt_][nt_] = MFMA(al_, wh_, acc[mt_][nt_]);                         \
    } } while (0)

// Body of sub-chunk s_: two M-tile groups of 2; stage AFTER all buffer reads.
#define SUB_BODY(s_, wCur_, wNxt_) do {                                        \
    SB();                                                                      \
    const unsigned char* ls_ = smem + (size_t)w * 16384 + ((s_) & 1) * 8192 + laneOff; \
    {                                                                          \
        float4 qa0_ = *reinterpret_cast<const float4*>(ls_ + 0 * 2048);        \
        float4 qa1_ = *reinterpret_cast<const float4*>(ls_ + 0 * 2048 + 1024); \
        float4 qa2_ = *reinterpret_cast<const float4*>(ls_ + 1 * 2048);        \
        float4 qa3_ = *reinterpret_cast<const float4*>(ls_ + 1 * 2048 + 1024); \
        WAITLG(); SB();                                                        \
        if ((((s_) & 1) == 0) && ((s_) / 2 + 1 < 8)) LOAD_W(wNxt_, (s_) / 2 + 1); \
        TILE_MFMA(qa0_, qa1_, ((s_) & 1) * 4 + 0, wCur_);                      \
        TILE_MFMA(qa2_, qa3_, ((s_) & 1) * 4 + 1, wCur_);                      \
    }                                                                          \
    SB();                                                                      \
    {                                                                          \
        float4 qb0_ = *reinterpret_cast<const float4*>(ls_ + 2 * 2048);        \
        float4 qb1_ = *reinterpret_cast<const float4*>(ls_ + 2 * 2048 + 1024); \
        float4 qb2_ = *reinterpret_cast<const float4*>(ls_ + 3 * 2048);        \
        float4 qb3_ = *reinterpret_cast<const float4*>(ls_ + 3 * 2048 + 1024); \
        WAITLG(); SB();                                                        \
        if ((s_) + 2 < 16) STAGE_S((s_) + 2);   /* all buf reads done: safe */ \
        TILE_MFMA(qb0_, qb1_, ((s_) & 1) * 4 + 2, wCur_);                      \
        TILE_MFMA(qb2_, qb3_, ((s_) & 1) * 4 + 3, wCur_);                      \
    }                                                                          \
} while (0)

// Steady-state in-flight at entry: even s: [W(t), stage(s), stage(s+1)] = 24
// -> vmcnt(8) drains W(t)+stage(s); odd s: [stage(s), W(t+1), stage(s+1)] = 24
// -> vmcnt(16) drains stage(s); s=15: [stage(15)] -> vmcnt(0).
#define SUB_E(s_, wC_, wN_) do { WAITVM(8);  SUB_BODY(s_, wC_, wN_); } while (0)
#define SUB_O(s_, wC_, wN_) do { WAITVM(16); SUB_BODY(s_, wC_, wN_); } while (0)
#define SUB_Z(s_, wC_, wN_) do { WAITVM(0);  SUB_BODY(s_, wC_, wN_); } while (0)

__global__ __launch_bounds__(512, 2) void router_gemm_partial(
    const float* __restrict__ A,
    const unsigned char* __restrict__ wsHi,   // frag-ordered W hi; lo at +512KB
    float* __restrict__ partG)                // [2][T][64] f32
{
    // [0,128K): per-wave A staging (wave w: [w*16K, +16K), 2 x 8 KB buffers).
    // Reused as the 128 KB combine scratch part[4][8][4][64] afterwards.
    __shared__ unsigned char smem[131072];

    const int tid  = threadIdx.x;
    const int lane = tid & 63;
    const int w    = tid >> 6;                // wave id (0..7) = K-sixteenth
    const int ky   = blockIdx.y;              // K-half (0..1)
    const int tok0 = blockIdx.x * 128;
    const int tBase = ky * 64 + w * 8;        // global chunk base (chunks of 32k)

    const float* aBase = A + (size_t)(tok0 + (lane & 15)) * HIDDEN
                           + ky * 2048 + w * 256 + ((lane >> 4) & 3) * 8;
    const int laneOff = lane * 16;

    f32x4 acc[8][4];
#pragma unroll
    for (int mt = 0; mt < 8; ++mt)
#pragma unroll
        for (int nt = 0; nt < 4; ++nt) acc[mt][nt] = (f32x4){0.f, 0.f, 0.f, 0.f};

    uint4 wX[8], wY[8];          // W ping-pong (hi 0..3, lo 4..7)

    // Prologue: W(0) first (oldest), then sub 0, sub 1.
    LOAD_W(wX, 0);
    STAGE_S(0);
    STAGE_S(1);

    SUB_E( 0, wX, wY);  SUB_O( 1, wX, wY);    // chunk 0 (W = wX)
    SUB_E( 2, wY, wX);  SUB_O( 3, wY, wX);    // chunk 1
    SUB_E( 4, wX, wY);  SUB_O( 5, wX, wY);    // chunk 2
    SUB_E( 6, wY, wX);  SUB_O( 7, wY, wX);    // chunk 3
    SUB_E( 8, wX, wY);  SUB_O( 9, wX, wY);    // chunk 4
    SUB_E(10, wY, wX);  SUB_O(11, wY, wX);    // chunk 5
    SUB_E(12, wX, wY);  SUB_O(13, wX, wY);    // chunk 6
    SUB_E(14, wY, wX);  SUB_Z(15, wY, wX);    // chunk 7

    // ---- in-block combine over 8 waves: 0-3 write, 4-7 RMW-add, then
    // wave w<4 reduces q=0..3 for M-tiles 2w,2w+1, writes fp32 partials.
    f32x4 (*part)[8][4][64] = reinterpret_cast<f32x4 (*)[8][4][64]>(smem);

    __syncthreads();
    if (w < 4) {
#pragma unroll
        for (int mt = 0; mt < 8; ++mt)
#pragma unroll
            for (int nt = 0; nt < 4; ++nt) part[w][mt][nt][lane] = acc[mt][nt];
    }
    __syncthreads();
    if (w >= 4) {
#pragma unroll
        for (int mt = 0; mt < 8; ++mt)
#pragma unroll
            for (int nt = 0; nt < 4; ++nt)
                part[w - 4][mt][nt][lane] = part[w - 4][mt][nt][lane] + acc[mt][nt];
    }
    __syncthreads();

    if (w < 4) {
#pragma unroll
        for (int j = 0; j < 2; ++j) {
            const int mt = 2 * w + j;
#pragma unroll
            for (int nt = 0; nt < 4; ++nt) {
                f32x4 s = part[0][mt][nt][lane];
#pragma unroll
                for (int q = 1; q < 4; ++q) s = s + part[q][mt][nt][lane];
                const int e = nt * 16 + (lane & 15);
#pragma unroll
                for (int r = 0; r < 4; ++r) {
                    const int tok = tok0 + mt * 16 + (lane >> 4) * 4 + r;
                    partG[((size_t)ky * T_TOKENS + tok) * 64 + e] = s[r];
                }
            }
        }
    }
}

// ---- combine kernel: sum the 2 K-halves per token, top-2 ----
__global__ __launch_bounds__(64) void combine_topk(
    const float* __restrict__ partG,   // [2][T][64]
    float* __restrict__ out)
{
    const int tok = blockIdx.x * 64 + threadIdx.x;
    const float4* p0 = reinterpret_cast<const float4*>(partG + (size_t)tok * 64);
    const float4* p1 = reinterpret_cast<const float4*>(partG + ((size_t)T_TOKENS + tok) * 64);

    float s[64];
#pragma unroll
    for (int i = 0; i < 16; ++i) {
        float4 a = p0[i], b = p1[i];
        s[4*i+0] = a.x + b.x; s[4*i+1] = a.y + b.y;
        s[4*i+2] = a.z + b.z; s[4*i+3] = a.w + b.w;
    }

    float b1 = -INFINITY, b2 = -INFINITY;
    int i1 = 0, i2 = 0;
#pragma unroll
    for (int e = 0; e < NUM_EXPERTS; ++e) {
        float v = s[e];
        if (v > b1)      { b2 = b1; i2 = i1; b1 = v; i1 = e; }
        else if (v > b2) { b2 = v;  i2 = e; }
    }
    out[(size_t)tok * 2 + 0] = b1;
    out[(size_t)tok * 2 + 1] = b2;
    out[(size_t)2 * T_TOKENS + (size_t)tok * 2 + 0] = (float)i1;
    out[(size_t)2 * T_TOKENS + (size_t)tok * 2 + 1] = (float)i2;
}

extern "C" void kernel_launch(void* const* d_in, const int* in_sizes, int n_in,
                              void* d_out, int out_size, void* d_ws, size_t ws_size,
                              hipStream_t stream) {
    const float* A = (const float*)d_in[0];   // hidden_states fp32 [16384,4096]
    const float* W = (const float*)d_in[1];   // W fp32 [64,4096]
    float* out = (float*)d_out;
    unsigned char* ws = (unsigned char*)d_ws;
    // ws layout: [0,1MB) W hi/lo planes; [1MB, 1MB+8MB) fp32 partials [2][T][64]
    float* partG = reinterpret_cast<float*>(ws + (1 << 20));

    w_split_kernel<<<dim3(128), dim3(256), 0, stream>>>(W, ws);
    router_gemm_partial<<<dim3(T_TOKENS / 128, 2), dim3(512), 0, stream>>>(A, ws, partG);
    combine_topk<<<dim3(T_TOKENS / 64), dim3(64), 0, stream>>>(partG, out);
}

// Round 18
// 61.051 us; speedup vs baseline: 1.2746x; 1.0641x over previous
//
#include <hip/hip_runtime.h>
#include <hip/hip_bf16.h>
#include <math.h>

#define NUM_EXPERTS 64
#define HIDDEN      4096
#define T_TOKENS    16384   // B*S

using short8 = __attribute__((ext_vector_type(8))) short;   // 8 bf16
using f32x4  = __attribute__((ext_vector_type(4))) float;

// (f0,f1) -> packed bf16 hi (f0 in low 16) + packed bf16 lo residuals.
__device__ __forceinline__ unsigned pack_pair(float f0, float f1, unsigned& lopk) {
    __hip_bfloat162 h2 = __float22bfloat162_rn(make_float2(f0, f1));
    unsigned hb; __builtin_memcpy(&hb, &h2, 4);
    float h0 = __builtin_bit_cast(float, hb << 16);
    float h1 = __builtin_bit_cast(float, hb & 0xffff0000u);
    __hip_bfloat162 l2 = __float22bfloat162_rn(make_float2(f0 - h0, f1 - h1));
    unsigned lb; __builtin_memcpy(&lb, &l2, 4);
    lopk = lb;
    return hb;
}
__device__ __forceinline__ void split8(const float4 a, const float4 b, uint4& hi, uint4& lo) {
    hi.x = pack_pair(a.x, a.y, lo.x);
    hi.y = pack_pair(a.z, a.w, lo.y);
    hi.z = pack_pair(b.x, b.y, lo.z);
    hi.w = pack_pair(b.z, b.w, lo.w);
}

#define MFMA(a, b, c) __builtin_amdgcn_mfma_f32_16x16x32_bf16((a), (b), (c), 0, 0, 0)

// async global->LDS, 16 B per lane (zero VGPR cost).
#define GLOAD16(g_, l_)                                                        \
    __builtin_amdgcn_global_load_lds(                                          \
        (__attribute__((address_space(1))) unsigned*)(void*)(g_),              \
        (__attribute__((address_space(3))) unsigned*)(void*)(l_), 16, 0, 0)

#define WAITVM(n_)  asm volatile("s_waitcnt vmcnt(" #n_ ")" ::: "memory")
#define WAITLG()    asm volatile("s_waitcnt lgkmcnt(0)" ::: "memory")
#define SB()        __builtin_amdgcn_sched_barrier(0)

// ---- pre-kernel: split W [64][4096] f32 into fragment-ordered bf16 hi/lo planes.
// Fragment j = ((t*4 + nt)*64 + lane), t = global K-chunk (k/32).
__global__ __launch_bounds__(256) void w_split_kernel(
    const float* __restrict__ W, unsigned char* __restrict__ ws)
{
    const int j  = blockIdx.x * 256 + threadIdx.x;   // 0..32767
    const int l  = j & 63;
    const int nt = (j >> 6) & 3;
    const int t  = j >> 8;
    const int e  = nt * 16 + (l & 15);
    const int k0 = t * 32 + ((l >> 4) & 3) * 8;
    const float* p = W + (size_t)e * HIDDEN + k0;
    float4 w0 = *reinterpret_cast<const float4*>(p);
    float4 w1 = *reinterpret_cast<const float4*>(p + 4);
    uint4 hi, lo;
    split8(w0, w1, hi, lo);
    *reinterpret_cast<uint4*>(ws + (size_t)j * 16)            = hi;
    *reinterpret_cast<uint4*>(ws + 524288 + (size_t)j * 16)   = lo;
}

// ---- main kernel: block = 128 tokens x K-half (blockIdx.y); 4 waves, each
// owning a K-eighth-of-total (512 k = 16 chunks) across 8 M-tiles.
// W traffic: 128 MB. Counted-vmcnt wave-private staging pipeline (R13/R14).

#define LOAD_W(dst, t_) do {                                                   \
    const unsigned char* pW_ = wsHi + (size_t)(tBase + (t_)) * 4096 + laneOff; \
    _Pragma("unroll")                                                          \
    for (int nt_ = 0; nt_ < 4; ++nt_) {                                        \
        dst[nt_]     = *reinterpret_cast<const uint4*>(pW_ + nt_ * 1024);      \
        dst[nt_ + 4] = *reinterpret_cast<const uint4*>(pW_ + 524288 + nt_ * 1024); \
    } } while (0)

// Stage one K=32 chunk of A (8 M-tiles) into wave-private buffer b_ (16 gload_lds).
#define STAGE_A8(b_, t_) do {                                                  \
    unsigned char* ld_ = smem + (size_t)w * 32768 + (b_) * 16384;              \
    const float* g0_ = aBase + (size_t)(t_) * 32;                              \
    _Pragma("unroll")                                                          \
    for (int mt_ = 0; mt_ < 8; ++mt_) {                                        \
        const float* g_ = g0_ + (size_t)mt_ * 16 * HIDDEN;                     \
        GLOAD16(g_,     ld_ + mt_ * 2048);                                     \
        GLOAD16(g_ + 4, ld_ + mt_ * 2048 + 1024);                              \
    } } while (0)

// ds_read for M-tiles mt0_..mt0_+3 from LDS base ls_.
#define SUB_READ(q_, ls_, mt0_) do {                                           \
    _Pragma("unroll")                                                          \
    for (int i_ = 0; i_ < 4; ++i_) {                                           \
        q_[i_][0] = *reinterpret_cast<const float4*>((ls_) + (mt0_ + i_) * 2048);        \
        q_[i_][1] = *reinterpret_cast<const float4*>((ls_) + (mt0_ + i_) * 2048 + 1024); \
    } } while (0)

#define SUB_MFMA(q_, mt0_, wb_) do {                                           \
    _Pragma("unroll")                                                          \
    for (int i_ = 0; i_ < 4; ++i_) {                                           \
        uint4 hi_, lo_;                                                        \
        split8(q_[i_][0], q_[i_][1], hi_, lo_);                                \
        short8 ah_ = __builtin_bit_cast(short8, hi_);                          \
        short8 al_ = __builtin_bit_cast(short8, lo_);                          \
        _Pragma("unroll")                                                      \
        for (int nt_ = 0; nt_ < 4; ++nt_) {                                    \
            short8 wh_ = __builtin_bit_cast(short8, wb_[nt_]);                 \
            short8 wl_ = __builtin_bit_cast(short8, wb_[nt_ + 4]);             \
            acc[mt0_ + i_][nt_] = MFMA(ah_, wh_, acc[mt0_ + i_][nt_]);         \
            acc[mt0_ + i_][nt_] = MFMA(ah_, wl_, acc[mt0_ + i_][nt_]);         \
            acc[mt0_ + i_][nt_] = MFMA(al_, wh_, acc[mt0_ + i_][nt_]);         \
        } } } while (0)

// One chunk. Steady state: entering, outstanding = [A(t),W(t),A(t+1)] = 40;
// vmcnt(16) drains A(t)+W(t), leaves A(t+1) in flight.
#define ITER_BODY(t_, buf_, wCur_, wNxt_) do {                                 \
    SB();                                                                      \
    const unsigned char* ls_ = smem + (size_t)w * 32768 + (buf_) * 16384 + laneOff; \
    float4 qA_[4][2];                                                          \
    SUB_READ(qA_, ls_, 0);                                                     \
    WAITLG(); SB();                                                            \
    if ((t_) + 1 < 16) LOAD_W(wNxt_, (t_) + 1);                                \
    SUB_MFMA(qA_, 0, wCur_);                                                   \
    float4 qB_[4][2];                                                          \
    SUB_READ(qB_, ls_, 4);                                                     \
    WAITLG(); SB();                                                            \
    if ((t_) + 2 < 16) STAGE_A8(buf_, (t_) + 2);                               \
    SUB_MFMA(qB_, 4, wCur_);                                                   \
} while (0)

#define ITER(t_, buf_, wCur_, wNxt_)      do { WAITVM(16); ITER_BODY(t_, buf_, wCur_, wNxt_); } while (0)
#define ITER_LAST(t_, buf_, wCur_, wNxt_) do { WAITVM(0);  ITER_BODY(t_, buf_, wCur_, wNxt_); } while (0)

__global__ __launch_bounds__(256, 1) void router_gemm_partial(
    const float* __restrict__ A,
    const unsigned char* __restrict__ wsHi,   // frag-ordered W hi; lo at +512KB
    float* __restrict__ partG)                // [2][T][64] f32
{
    // [0,128K): per-wave A staging (wave w: [w*32K, +32K), 2 x 16 KB buffers).
    // Reused as the 128 KB in-block combine scratch after the main loop.
    __shared__ unsigned char smem[131072];

    const int tid  = threadIdx.x;
    const int lane = tid & 63;
    const int w    = tid >> 6;                // wave id = K-quarter of half (0..3)
    const int ky   = blockIdx.y;              // K-half (0..1)
    const int tok0 = blockIdx.x * 128;
    const int tBase = ky * 64 + w * 16;       // global chunk base (chunks of 32k)

    const float* aBase = A + (size_t)(tok0 + (lane & 15)) * HIDDEN
                           + ky * 2048 + w * 512 + ((lane >> 4) & 3) * 8;
    const int laneOff = lane * 16;

    f32x4 acc[8][4];
#pragma unroll
    for (int mt = 0; mt < 8; ++mt)
#pragma unroll
        for (int nt = 0; nt < 4; ++nt) acc[mt][nt] = (f32x4){0.f, 0.f, 0.f, 0.f};

    uint4 wX[8], wY[8];          // W ping-pong (hi 0..3, lo 4..7)

    // Prologue: W(0) first (oldest), then A(0), A(1).
    LOAD_W(wX, 0);
    STAGE_A8(0, 0);
    STAGE_A8(1, 1);

    ITER( 0, 0, wX, wY);  ITER( 1, 1, wY, wX);
    ITER( 2, 0, wX, wY);  ITER( 3, 1, wY, wX);
    ITER( 4, 0, wX, wY);  ITER( 5, 1, wY, wX);
    ITER( 6, 0, wX, wY);  ITER( 7, 1, wY, wX);
    ITER( 8, 0, wX, wY);  ITER( 9, 1, wY, wX);
    ITER(10, 0, wX, wY);  ITER(11, 1, wY, wX);
    ITER(12, 0, wX, wY);  ITER(13, 1, wY, wX);
    ITER(14, 0, wX, wY);  ITER_LAST(15, 1, wY, wX);

    // ---- in-block combine over 4 K-quarters (reuse smem as part[4][8][4][64])
    f32x4 (*part)[8][4][64] = reinterpret_cast<f32x4 (*)[8][4][64]>(smem);

    __syncthreads();
#pragma unroll
    for (int mt = 0; mt < 8; ++mt)
#pragma unroll
        for (int nt = 0; nt < 4; ++nt) part[w][mt][nt][lane] = acc[mt][nt];
    __syncthreads();

    // wave w reduces M-tiles 2w, 2w+1 and writes fp32 partials to global.
#pragma unroll
    for (int j = 0; j < 2; ++j) {
        const int mt = 2 * w + j;
#pragma unroll
        for (int nt = 0; nt < 4; ++nt) {
            f32x4 s = part[0][mt][nt][lane];
#pragma unroll
            for (int q = 1; q < 4; ++q) s = s + part[q][mt][nt][lane];
            const int e = nt * 16 + (lane & 15);
#pragma unroll
            for (int r = 0; r < 4; ++r) {
                const int tok = tok0 + mt * 16 + (lane >> 4) * 4 + r;
                partG[((size_t)ky * T_TOKENS + tok) * 64 + e] = s[r];
            }
        }
    }
}

// ---- combine kernel: sum the 2 K-halves per token, top-2 ----
__global__ __launch_bounds__(64) void combine_topk(
    const float* __restrict__ partG,   // [2][T][64]
    float* __restrict__ out)
{
    const int tok = blockIdx.x * 64 + threadIdx.x;
    const float4* p0 = reinterpret_cast<const float4*>(partG + (size_t)tok * 64);
    const float4* p1 = reinterpret_cast<const float4*>(partG + ((size_t)T_TOKENS + tok) * 64);

    float s[64];
#pragma unroll
    for (int i = 0; i < 16; ++i) {
        float4 a = p0[i], b = p1[i];
        s[4*i+0] = a.x + b.x; s[4*i+1] = a.y + b.y;
        s[4*i+2] = a.z + b.z; s[4*i+3] = a.w + b.w;
    }

    float b1 = -INFINITY, b2 = -INFINITY;
    int i1 = 0, i2 = 0;
#pragma unroll
    for (int e = 0; e < NUM_EXPERTS; ++e) {
        float v = s[e];
        if (v > b1)      { b2 = b1; i2 = i1; b1 = v; i1 = e; }
        else if (v > b2) { b2 = v;  i2 = e; }
    }
    out[(size_t)tok * 2 + 0] = b1;
    out[(size_t)tok * 2 + 1] = b2;
    out[(size_t)2 * T_TOKENS + (size_t)tok * 2 + 0] = (float)i1;
    out[(size_t)2 * T_TOKENS + (size_t)tok * 2 + 1] = (float)i2;
}

extern "C" void kernel_launch(void* const* d_in, const int* in_sizes, int n_in,
                              void* d_out, int out_size, void* d_ws, size_t ws_size,
                              hipStream_t stream) {
    const float* A = (const float*)d_in[0];   // hidden_states fp32 [16384,4096]
    const float* W = (const float*)d_in[1];   // W fp32 [64,4096]
    float* out = (float*)d_out;
    unsigned char* ws = (unsigned char*)d_ws;
    // ws layout: [0,1MB) W hi/lo planes; [1MB, 1MB+8MB) fp32 partials [2][T][64]
    float* partG = reinterpret_cast<float*>(ws + (1 << 20));

    w_split_kernel<<<dim3(128), dim3(256), 0, stream>>>(W, ws);
    router_gemm_partial<<<dim3(T_TOKENS / 128, 2), dim3(256), 0, stream>>>(A, ws, partG);
    combine_topk<<<dim3(T_TOKENS / 64), dim3(64), 0, stream>>>(partG, out);
}